// Round 6
// baseline (2920.747 us; speedup 1.0000x reference)
//
#include <hip/hip_runtime.h>
#include <hip/hip_bf16.h>
#include <cstddef>

#define NROW 4096
#define DIM  512
static const size_t NP = (size_t)NROW * NROW;   // 16777216
#define L2E   1.4426950408889634f
#define ALPHA2 (-12.0f)          // (-ln 4096) * log2e == -log2(4096), exact
#define QSCALE 64.0f             // S fp32 -> int16: q = rn(S*64), |S| < 512 guaranteed
#define QD    (1.4426950408889634f / 64.0f)   // dequant * log2e folded into one fma

typedef unsigned int uint32;

// ---------------------------------------------------------------- sq norms
__global__ __launch_bounds__(256) void sqnorm_kernel(const float* __restrict__ x,
                                                     const float* __restrict__ y,
                                                     float* __restrict__ x2,
                                                     float* __restrict__ y2) {
    int gtid = blockIdx.x * 256 + threadIdx.x;
    int wid  = gtid >> 6;          // 8192 waves: 0..4095 -> x, 4096..8191 -> y
    int lane = gtid & 63;
    const float* src = (wid < NROW) ? x : y;
    float*       dst = (wid < NROW) ? x2 : y2;
    int row = (wid < NROW) ? wid : (wid - NROW);
    const float4* r4 = (const float4*)(src + (size_t)row * DIM);
    float4 a = r4[lane];
    float4 b = r4[lane + 64];
    float s = a.x*a.x + a.y*a.y + a.z*a.z + a.w*a.w
            + b.x*b.x + b.y*b.y + b.z*b.z + b.w*b.w;
    #pragma unroll
    for (int off = 32; off > 0; off >>= 1) s += __shfl_down(s, off);
    if (lane == 0) dst[row] = s;
}

// ---------------------------------------------------------------- S = 2 x y^T  (fp32)
__global__ __launch_bounds__(256) void gemm_kernel(const float* __restrict__ A,
                                                   const float* __restrict__ B,
                                                   float* __restrict__ S) {
    __shared__ float As[16][132];
    __shared__ float Bs[16][132];
    const int bm = blockIdx.y * 128, bn = blockIdx.x * 128;
    const int tid = threadIdx.x;
    const int tx = tid & 15, ty = tid >> 4;
    float acc[8][8];
    #pragma unroll
    for (int i = 0; i < 8; ++i)
        #pragma unroll
        for (int j = 0; j < 8; ++j) acc[i][j] = 0.f;

    for (int kt = 0; kt < DIM; kt += 16) {
        #pragma unroll
        for (int h = 0; h < 2; ++h) {
            int f = tid + h * 256;
            int row = f >> 2, kk = (f & 3) << 2;
            float4 a4 = *(const float4*)(A + (size_t)(bm + row) * DIM + kt + kk);
            As[kk+0][row] = a4.x; As[kk+1][row] = a4.y;
            As[kk+2][row] = a4.z; As[kk+3][row] = a4.w;
            float4 b4 = *(const float4*)(B + (size_t)(bn + row) * DIM + kt + kk);
            Bs[kk+0][row] = b4.x; Bs[kk+1][row] = b4.y;
            Bs[kk+2][row] = b4.z; Bs[kk+3][row] = b4.w;
        }
        __syncthreads();
        #pragma unroll
        for (int k = 0; k < 16; ++k) {
            float ar[8], br[8];
            #pragma unroll
            for (int i = 0; i < 8; ++i) ar[i] = As[k][ty*8 + i];
            #pragma unroll
            for (int j = 0; j < 8; ++j) br[j] = Bs[k][tx*8 + j];
            #pragma unroll
            for (int i = 0; i < 8; ++i)
                #pragma unroll
                for (int j = 0; j < 8; ++j)
                    acc[i][j] = __fmaf_rn(ar[i], br[j], acc[i][j]);
        }
        __syncthreads();
    }
    #pragma unroll
    for (int i = 0; i < 8; ++i) {
        size_t off = (size_t)(bm + ty*8 + i) * NROW + bn + tx*8;
        #pragma unroll
        for (int j = 0; j < 8; ++j) S[off + j] = 2.0f * acc[i][j];
    }
}

// ---------------------------------------------------------------- quantize S -> Sq (row-major int16 pairs)
__global__ __launch_bounds__(256) void quantA_kernel(const float* __restrict__ S,
                                                     uint32* __restrict__ Sq) {
    size_t i = (size_t)blockIdx.x * 256 + threadIdx.x;     // uint index
    const size_t nu = NP / 2, stride = (size_t)2048 * 256;
    for (; i < nu; i += stride) {
        float a = S[2*i], b = S[2*i + 1];
        float qa = fmaxf(fminf(a * QSCALE,  32767.f), -32767.f);
        float qb = fmaxf(fminf(b * QSCALE,  32767.f), -32767.f);
        int ia = __float2int_rn(qa), ib = __float2int_rn(qb);
        Sq[i] = (uint32)(ia & 0xffff) | ((uint32)ib << 16);
    }
}

// ---------------------------------------------------------------- quantize+transpose S -> SqT
__global__ __launch_bounds__(256) void quantT_kernel(const float* __restrict__ S,
                                                     uint32* __restrict__ SqT) {
    __shared__ short tile[64][66];
    const int bx = blockIdx.x * 64, by = blockIdx.y * 64;  // bx: col block, by: row block
    const int t = threadIdx.x;
    const int c = t & 63, r0 = t >> 6;                     // read: 64 consecutive cols per wave
    #pragma unroll
    for (int rr = 0; rr < 16; ++rr) {
        int r = r0 + rr * 4;
        float v = S[(size_t)(by + r) * NROW + bx + c];
        float q = fmaxf(fminf(v * QSCALE, 32767.f), -32767.f);
        tile[r][c] = (short)__float2int_rn(q);
    }
    __syncthreads();
    // write: SqT row j = bx + jcol, packed i-pairs (by + 2p, by + 2p + 1)
    const int p = t & 31, jl = t >> 5;                     // 32 pairs, 8 local cols
    #pragma unroll
    for (int jj = 0; jj < 8; ++jj) {
        int j = jj * 8 + jl;
        uint32 lo = (unsigned short)tile[2*p    ][j];
        uint32 hi = (unsigned short)tile[2*p + 1][j];
        SqT[(size_t)(bx + j) * (NROW/2) + (by >> 1) + p] = lo | (hi << 16);
    }
}

// ---------------------------------------------------------------- init
__global__ void init_kernel(const float* __restrict__ y2,
                            float* __restrict__ gt2,
                            float* __restrict__ cost) {
    int i = blockIdx.x * 256 + threadIdx.x;
    if (i < NROW) gt2[i] = -y2[i] * L2E;       // g~0 = -y2, in base-2 units
    if (i == 0) cost[0] = 0.f;
}

// ---------------------------------------------------------------- lse pass (quantized, base-2, defer-max)
// o2[r] = -12 - log2( sum_j 2^( u2[j] + q[r][j]*QD ) ),  2 rows per block
__global__ __launch_bounds__(256) void lseq_kernel(const uint32* __restrict__ Q,
                                                   const float* __restrict__ u2,
                                                   float* __restrict__ o2) {
    const int r0 = blockIdx.x * 2;
    const uint32* q0 = Q + (size_t)r0 * (NROW/2);
    const uint32* q1 = q0 + (NROW/2);
    const int t = threadIdx.x;
    float m0 = -1e30f, s0 = 0.f, m1 = -1e30f, s1 = 0.f;
    #pragma unroll
    for (int h = 0; h < 8; ++h) {
        int k = t + h * 256;                          // int16-pair index
        float2 uu = *(const float2*)(u2 + 2*k);       // ws -> 8B aligned
        uint32 w0 = q0[k], w1 = q1[k];
        float a0 = (float)(int)(short)(w0 & 0xffffu);
        float b0 = (float)((int)w0 >> 16);
        float a1 = (float)(int)(short)(w1 & 0xffffu);
        float b1 = (float)((int)w1 >> 16);
        float v00 = fmaf(a0, QD, uu.x), v01 = fmaf(b0, QD, uu.y);
        float v10 = fmaf(a1, QD, uu.x), v11 = fmaf(b1, QD, uu.y);
        float vm0 = fmaxf(v00, v01), vm1 = fmaxf(v10, v11);
        if (__any(vm0 > m0 + 60.f)) {                 // rare wave-uniform rescale
            float mn = fmaxf(m0, vm0);
            s0 *= exp2f(m0 - mn); m0 = mn;
        }
        if (__any(vm1 > m1 + 60.f)) {
            float mn = fmaxf(m1, vm1);
            s1 *= exp2f(m1 - mn); m1 = mn;
        }
        s0 += exp2f(v00 - m0) + exp2f(v01 - m0);
        s1 += exp2f(v10 - m1) + exp2f(v11 - m1);
    }
    // wave butterfly merge (one trans per step per row)
    #pragma unroll
    for (int off = 1; off < 64; off <<= 1) {
        float mo = __shfl_xor(m0, off), so = __shfl_xor(s0, off);
        float d = m0 - mo;
        float e = exp2f(-fabsf(d));
        s0 = (d > 0.f) ? fmaf(so, e, s0) : fmaf(s0, e, so);
        m0 = fmaxf(m0, mo);
        float mo1 = __shfl_xor(m1, off), so1 = __shfl_xor(s1, off);
        float d1 = m1 - mo1;
        float e1 = exp2f(-fabsf(d1));
        s1 = (d1 > 0.f) ? fmaf(so1, e1, s1) : fmaf(s1, e1, so1);
        m1 = fmaxf(m1, mo1);
    }
    __shared__ float sm0[4], ss0[4], sm1[4], ss1[4];
    int lane = t & 63, w = t >> 6;
    if (lane == 0) { sm0[w] = m0; ss0[w] = s0; sm1[w] = m1; ss1[w] = s1; }
    __syncthreads();
    if (t == 0) {
        float M0 = sm0[0], S0 = ss0[0], M1 = sm1[0], S1 = ss1[0];
        #pragma unroll
        for (int ww = 1; ww < 4; ++ww) {
            float d = M0 - sm0[ww];
            float e = exp2f(-fabsf(d));
            S0 = (d > 0.f) ? fmaf(ss0[ww], e, S0) : fmaf(S0, e, ss0[ww]);
            M0 = fmaxf(M0, sm0[ww]);
            float d1 = M1 - sm1[ww];
            float e1 = exp2f(-fabsf(d1));
            S1 = (d1 > 0.f) ? fmaf(ss1[ww], e1, S1) : fmaf(S1, e1, ss1[ww]);
            M1 = fmaxf(M1, sm1[ww]);
        }
        o2[r0]     = ALPHA2 - (M0 + __log2f(S0));
        o2[r0 + 1] = ALPHA2 - (M1 + __log2f(S1));
    }
}

// ---------------------------------------------------------------- finalize
// pi = 2^(ft2_i + gt2_j + S*L2E); C = max(x2_i + y2_j - S, 0); cost += pi*C
__global__ __launch_bounds__(256) void finalize_kernel(const float* __restrict__ S,
                                                       const float* __restrict__ ft2,
                                                       const float* __restrict__ gt2,
                                                       const float* __restrict__ x2,
                                                       const float* __restrict__ y2,
                                                       float* __restrict__ pi,
                                                       float* __restrict__ C,
                                                       float* __restrict__ cost) {
    const int row = blockIdx.x;
    const size_t base = (size_t)row * NROW;
    const float fi2 = ft2[row];
    const float x2i = x2[row];
    float acc = 0.f;
    #pragma unroll
    for (int h = 0; h < 16; ++h) {
        int j = threadIdx.x + h * 256;
        float sv = S[base + j];                    // read BEFORE in-place C write
        float p  = exp2f(fmaf(sv, L2E, fi2 + gt2[j]));
        float c  = fmaxf(x2i + y2[j] - sv, 0.f);
        pi[base + j] = p;                          // clobbers Sq region (no longer needed)
        C[base + j]  = c;
        acc = __fmaf_rn(p, c, acc);
    }
    #pragma unroll
    for (int off = 32; off > 0; off >>= 1) acc += __shfl_down(acc, off);
    __shared__ float sa[4];
    int lane = threadIdx.x & 63, w = threadIdx.x >> 6;
    if (lane == 0) sa[w] = acc;
    __syncthreads();
    if (threadIdx.x == 0)
        atomicAdd(cost, sa[0] + sa[1] + sa[2] + sa[3]);
}

// ---------------------------------------------------------------- launch
extern "C" void kernel_launch(void* const* d_in, const int* in_sizes, int n_in,
                              void* d_out, int out_size, void* d_ws, size_t ws_size,
                              hipStream_t stream) {
    const float* x = (const float*)d_in[0];
    const float* y = (const float*)d_in[1];
    float* out  = (float*)d_out;
    float* cost = out;                 // [1]
    float* pi   = out + 1;             // [NP] floats; holds Sq|SqT (int16) during iters
    float* Cpt  = out + 1 + NP;        // [NP] floats; holds fp32 S during iters
    float* S    = Cpt;
    uint32* Sq  = (uint32*)pi;                 // NP/2 uints = 32 MB
    uint32* SqT = Sq + NP/2;                   // NP/2 uints = 32 MB (fills pi slot exactly)

    float* ws  = (float*)d_ws;         // small vectors only
    float* x2  = ws;
    float* y2  = ws + NROW;
    float* ft2 = ws + 2 * NROW;        // f~ in base-2 units
    float* gt2 = ws + 3 * NROW;        // g~ in base-2 units

    sqnorm_kernel<<<2048, 256, 0, stream>>>(x, y, x2, y2);
    gemm_kernel<<<dim3(32, 32), 256, 0, stream>>>(x, y, S);
    quantA_kernel<<<2048, 256, 0, stream>>>(S, Sq);
    quantT_kernel<<<dim3(64, 64), 256, 0, stream>>>(S, SqT);
    init_kernel<<<16, 256, 0, stream>>>(y2, gt2, cost);

    for (int it = 0; it < 100; ++it) {
        lseq_kernel<<<2048, 256, 0, stream>>>(Sq,  gt2, ft2);   // f update
        lseq_kernel<<<2048, 256, 0, stream>>>(SqT, ft2, gt2);   // g update
    }

    finalize_kernel<<<NROW, 256, 0, stream>>>(S, ft2, gt2, x2, y2, pi, Cpt, cost);
}